// Round 1
// baseline (1353.644 us; speedup 1.0000x reference)
//
#include <hip/hip_runtime.h>

typedef unsigned short u16;
typedef unsigned int u32;

typedef __attribute__((ext_vector_type(4))) float floatx4;
typedef __attribute__((ext_vector_type(8))) __bf16 bf16x8;

typedef __attribute__((address_space(3))) u32 lds_u32_t;
typedef __attribute__((address_space(1))) u32 glb_u32_t;

__device__ __forceinline__ void gld_lds16(const u16* g, u16* l) {
    __builtin_amdgcn_global_load_lds((glb_u32_t*)g, (lds_u32_t*)l, 16, 0, 0);
}

__device__ __forceinline__ u16 f2bf(float f) {
    u32 u = __float_as_uint(f);
    u += 0x7fffu + ((u >> 16) & 1u);
    return (u16)(u >> 16);
}
// pack two fp32 -> two bf16 (RNE) in one u32
__device__ __forceinline__ u32 pk2(float a, float b) {
    u32 x = __float_as_uint(a), y = __float_as_uint(b);
    x += 0x7fffu + ((x >> 16) & 1u);
    y += 0x7fffu + ((y >> 16) & 1u);
    return (x >> 16) | (y & 0xffff0000u);
}

#define BM 128
#define BN 128
#define BK 32

// elementwise f32 -> bf16, 8 elems/thread (count must be multiple of 2048*8)
__global__ __launch_bounds__(256) void convert_f32_bf16(
    const float* __restrict__ src, u16* __restrict__ dst)
{
    const size_t i = ((size_t)blockIdx.x * 256 + threadIdx.x) * 8;
    float4 a = *(const float4*)(src + i);
    float4 b = *(const float4*)(src + i + 4);
    *(uint4*)(dst + i) = make_uint4(pk2(a.x, a.y), pk2(a.z, a.w),
                                    pk2(b.x, b.y), pk2(b.z, b.w));
}

// C_bf16[M,N] = A_bf16[M,K] @ Bt_bf16[N,K]^T + bias_f32[N]
// m97 structure: 128x128 tile, BK=32, global_load_lds(16B) both operands.
__global__ __launch_bounds__(256, 2) void gemm_a16_c16(
    const u16* __restrict__ A, int lda,
    const u16* __restrict__ Bt,
    const float* __restrict__ bias,
    u16* __restrict__ C, int ldc,
    int K)
{
    __shared__ __align__(16) u16 sA[BM * BK];
    __shared__ __align__(16) u16 sB[BN * BK];
    const int tid  = threadIdx.x;
    const int bm   = blockIdx.x, bn = blockIdx.y;
    const int lane = tid & 63,  wave = tid >> 6;
    const int wm   = wave >> 1, wn   = wave & 1;
    const int l15  = lane & 15, quad = lane >> 4;

    const int sr = tid >> 2;          // 0..63
    const int sc = (tid & 3) * 8;     // 0,8,16,24
    const u16* gA0 = A  + (size_t)(bm * BM + sr) * lda + sc;
    const u16* gA1 = gA0 + (size_t)64 * lda;
    const u16* gB0 = Bt + (size_t)(bn * BN + sr) * K + sc;
    const u16* gB1 = gB0 + (size_t)64 * K;
    u16* lA0 = &sA[tid * 8];  u16* lA1 = &sA[2048 + tid * 8];
    u16* lB0 = &sB[tid * 8];  u16* lB1 = &sB[2048 + tid * 8];

    floatx4 acc[4][4] = {};

    for (int k0 = 0; k0 < K; k0 += BK) {
        __syncthreads();
        gld_lds16(gA0 + k0, lA0);
        gld_lds16(gA1 + k0, lA1);
        gld_lds16(gB0 + k0, lB0);
        gld_lds16(gB1 + k0, lB1);
        __syncthreads();

        bf16x8 af[4], bfr[4];
#pragma unroll
        for (int mi = 0; mi < 4; mi++)
            af[mi] = *(const bf16x8*)&sA[(wm * 64 + mi * 16 + l15) * BK + quad * 8];
#pragma unroll
        for (int ni = 0; ni < 4; ni++)
            bfr[ni] = *(const bf16x8*)&sB[(wn * 64 + ni * 16 + l15) * BK + quad * 8];
#pragma unroll
        for (int mi = 0; mi < 4; mi++)
#pragma unroll
            for (int ni = 0; ni < 4; ni++)
                acc[mi][ni] = __builtin_amdgcn_mfma_f32_16x16x32_bf16(
                    af[mi], bfr[ni], acc[mi][ni], 0, 0, 0);
    }

    const int row0 = bm * BM + wm * 64 + quad * 4;
    const int col0 = bn * BN + wn * 64 + l15;
#pragma unroll
    for (int mi = 0; mi < 4; mi++) {
#pragma unroll
        for (int ni = 0; ni < 4; ni++) {
            const int col = col0 + ni * 16;
            const float bv = bias[col];
#pragma unroll
            for (int r = 0; r < 4; r++) {
                const int row = row0 + mi * 16 + r;
                C[(size_t)row * ldc + col] = f2bf(acc[mi][ni][r] + bv);
            }
        }
    }
}

// C_f32[M,N] = A_bf16[M,K] @ Bt_bf16[N,K]^T + bias_f32[N] + R_f32[M,N]
__global__ __launch_bounds__(256, 2) void gemm_a16_c32(
    const u16* __restrict__ A, int lda,
    const u16* __restrict__ Bt,
    const float* __restrict__ bias,
    const float* __restrict__ R, int ldr,
    float* __restrict__ C, int ldc,
    int K)
{
    __shared__ __align__(16) u16 sA[BM * BK];
    __shared__ __align__(16) u16 sB[BN * BK];
    const int tid  = threadIdx.x;
    const int bm   = blockIdx.x, bn = blockIdx.y;
    const int lane = tid & 63,  wave = tid >> 6;
    const int wm   = wave >> 1, wn   = wave & 1;
    const int l15  = lane & 15, quad = lane >> 4;

    const int sr = tid >> 2;
    const int sc = (tid & 3) * 8;
    const u16* gA0 = A  + (size_t)(bm * BM + sr) * lda + sc;
    const u16* gA1 = gA0 + (size_t)64 * lda;
    const u16* gB0 = Bt + (size_t)(bn * BN + sr) * K + sc;
    const u16* gB1 = gB0 + (size_t)64 * K;
    u16* lA0 = &sA[tid * 8];  u16* lA1 = &sA[2048 + tid * 8];
    u16* lB0 = &sB[tid * 8];  u16* lB1 = &sB[2048 + tid * 8];

    floatx4 acc[4][4] = {};

    for (int k0 = 0; k0 < K; k0 += BK) {
        __syncthreads();
        gld_lds16(gA0 + k0, lA0);
        gld_lds16(gA1 + k0, lA1);
        gld_lds16(gB0 + k0, lB0);
        gld_lds16(gB1 + k0, lB1);
        __syncthreads();

        bf16x8 af[4], bfr[4];
#pragma unroll
        for (int mi = 0; mi < 4; mi++)
            af[mi] = *(const bf16x8*)&sA[(wm * 64 + mi * 16 + l15) * BK + quad * 8];
#pragma unroll
        for (int ni = 0; ni < 4; ni++)
            bfr[ni] = *(const bf16x8*)&sB[(wn * 64 + ni * 16 + l15) * BK + quad * 8];
#pragma unroll
        for (int mi = 0; mi < 4; mi++)
#pragma unroll
            for (int ni = 0; ni < 4; ni++)
                acc[mi][ni] = __builtin_amdgcn_mfma_f32_16x16x32_bf16(
                    af[mi], bfr[ni], acc[mi][ni], 0, 0, 0);
    }

    const int row0 = bm * BM + wm * 64 + quad * 4;
    const int col0 = bn * BN + wn * 64 + l15;
#pragma unroll
    for (int mi = 0; mi < 4; mi++) {
#pragma unroll
        for (int ni = 0; ni < 4; ni++) {
            const int col = col0 + ni * 16;
            const float bv = bias[col];
#pragma unroll
            for (int r = 0; r < 4; r++) {
                const int row = row0 + mi * 16 + r;
                C[(size_t)row * ldc + col] =
                    acc[mi][ni][r] + bv + R[(size_t)row * ldr + col];
            }
        }
    }
}

#define AW 136  // padded LDS row width (floats)

// Per-position cross-head attention: one wave per (b,t); H=8, HD=128.
// Q (bf16, qstride), KV (bf16, kvstride; per head g: [k(128)|v(128)]).
// Writes O in-place over Q (same-wave read-before-write only).
__global__ __launch_bounds__(256) void attn8(
    const u16* Q,
    const u16* __restrict__ KV,
    u16* O,
    int qstride, int kvstride)
{
    __shared__ __align__(16) float lds[4 * (3 * 8 * AW + 64)];
    const int wid = threadIdx.x >> 6, lane = threadIdx.x & 63;
    float* qs = lds + wid * (3 * 8 * AW + 64);
    float* ks = qs + 8 * AW;
    float* vs = ks + 8 * AW;
    float* ws = vs + 8 * AW;
    const size_t pos = (size_t)blockIdx.x * 4 + wid;
    const u16* qrow  = Q  + pos * qstride;
    const u16* kvrow = KV + pos * kvstride;

#pragma unroll
    for (int it = 0; it < 2; it++) {
        int vi = lane + 64 * it;          // 0..127 (8 bf16 each)
        int h = vi >> 4, c = (vi & 15) * 8;
        uint4 r = *(const uint4*)(qrow + vi * 8);
        float f0 = __uint_as_float(r.x << 16), f1 = __uint_as_float(r.x & 0xffff0000u);
        float f2 = __uint_as_float(r.y << 16), f3 = __uint_as_float(r.y & 0xffff0000u);
        float f4 = __uint_as_float(r.z << 16), f5 = __uint_as_float(r.z & 0xffff0000u);
        float f6 = __uint_as_float(r.w << 16), f7 = __uint_as_float(r.w & 0xffff0000u);
        float4* d = (float4*)&qs[h * AW + c];
        d[0] = make_float4(f0, f1, f2, f3);
        d[1] = make_float4(f4, f5, f6, f7);
    }
#pragma unroll
    for (int it = 0; it < 4; it++) {
        int vi = lane + 64 * it;          // 0..255
        int g = vi >> 5, c = (vi & 31) * 8;   // 0..248
        uint4 r = *(const uint4*)(kvrow + vi * 8);
        float f0 = __uint_as_float(r.x << 16), f1 = __uint_as_float(r.x & 0xffff0000u);
        float f2 = __uint_as_float(r.y << 16), f3 = __uint_as_float(r.y & 0xffff0000u);
        float f4 = __uint_as_float(r.z << 16), f5 = __uint_as_float(r.z & 0xffff0000u);
        float f6 = __uint_as_float(r.w << 16), f7 = __uint_as_float(r.w & 0xffff0000u);
        float* base = (c < 128) ? &ks[g * AW + c] : &vs[g * AW + (c - 128)];
        ((float4*)base)[0] = make_float4(f0, f1, f2, f3);
        ((float4*)base)[1] = make_float4(f4, f5, f6, f7);
    }
    __syncthreads();

    // scores: lane = h*8+g
    const int h = lane >> 3, g = lane & 7;
    float s = 0.f;
#pragma unroll 8
    for (int d = 0; d < 128; d += 4) {
        float4 qv = *(const float4*)&qs[h * AW + d];
        float4 kv = *(const float4*)&ks[g * AW + d];
        s += qv.x * kv.x + qv.y * kv.y + qv.z * kv.z + qv.w * kv.w;
    }
    s *= 0.08838834764831845f;   // 1/sqrt(128)
    float m = s;
    m = fmaxf(m, __shfl_xor(m, 1, 64));
    m = fmaxf(m, __shfl_xor(m, 2, 64));
    m = fmaxf(m, __shfl_xor(m, 4, 64));
    float p = __expf(s - m);
    float sum = p;
    sum += __shfl_xor(sum, 1, 64);
    sum += __shfl_xor(sum, 2, 64);
    sum += __shfl_xor(sum, 4, 64);
    ws[lane] = p / sum;
    __syncthreads();

    // PV: lane owns (h = lane>>3, 16-col slab db = lane&7)
    const int db = lane & 7;
    float o[16];
#pragma unroll
    for (int j = 0; j < 16; j++) o[j] = 0.f;
#pragma unroll
    for (int g2 = 0; g2 < 8; g2++) {
        float wv = ws[h * 8 + g2];
        const float* vr = &vs[g2 * AW + db * 16];
#pragma unroll
        for (int j = 0; j < 16; j++) o[j] += wv * vr[j];
    }
    u16* orow = O + pos * qstride + h * 128 + db * 16;
    u32 pk[8];
#pragma unroll
    for (int j = 0; j < 8; j++)
        pk[j] = (u32)f2bf(o[2 * j]) | ((u32)f2bf(o[2 * j + 1]) << 16);
    ((uint4*)orow)[0] = make_uint4(pk[0], pk[1], pk[2], pk[3]);
    ((uint4*)orow)[1] = make_uint4(pk[4], pk[5], pk[6], pk[7]);
}

// src f32 (K,N) row-major -> dst bf16 (N,K) row-major
__global__ __launch_bounds__(256) void transpose_f32_bf16(
    const float* __restrict__ src, u16* __restrict__ dst, int K, int N)
{
    __shared__ float tile[32][33];
    const int tx = threadIdx.x & 31, ty = threadIdx.x >> 5;
    const int c0 = blockIdx.x * 32, r0 = blockIdx.y * 32;
#pragma unroll
    for (int i = 0; i < 4; i++)
        tile[ty + i * 8][tx] = src[(size_t)(r0 + ty + i * 8) * N + c0 + tx];
    __syncthreads();
#pragma unroll
    for (int i = 0; i < 4; i++)
        dst[(size_t)(c0 + ty + i * 8) * K + r0 + tx] = f2bf(tile[tx][ty + i * 8]);
}

extern "C" void kernel_launch(void* const* d_in, const int* in_sizes, int n_in,
                              void* d_out, int out_size, void* d_ws, size_t ws_size,
                              hipStream_t stream) {
    const float* liquid = (const float*)d_in[0];
    const float* mamba  = (const float*)d_in[1];
    const float* Wlq  = (const float*)d_in[2];
    const float* blq  = (const float*)d_in[3];
    const float* Wmkv = (const float*)d_in[4];
    const float* bmkv = (const float*)d_in[5];
    const float* Wmq  = (const float*)d_in[6];
    const float* bmq  = (const float*)d_in[7];
    const float* Wlkv = (const float*)d_in[8];
    const float* blkv = (const float*)d_in[9];
    const float* Wlo  = (const float*)d_in[10];
    const float* blo  = (const float*)d_in[11];
    const float* Wmo  = (const float*)d_in[12];
    const float* bmo  = (const float*)d_in[13];
    float* out = (float*)d_out;   // [enhanced_liquid | enhanced_mamba], each 32768x1024 fp32

    // workspace carve (bf16), peak ~208 MB (unchanged)
    u16* p = (u16*)d_ws;
    u16* WtLq  = p; p += (size_t)1024 * 1024;
    u16* WtLkv = p; p += (size_t)2048 * 1024;
    u16* WtMq  = p; p += (size_t)1024 * 1024;
    u16* WtMkv = p; p += (size_t)2048 * 1024;
    u16* WtLo  = p; p += (size_t)1024 * 1024;
    u16* WtMo  = p; p += (size_t)1024 * 1024;
    u16* Q  = p; p += (size_t)32768 * 1024;   // q_l -> a_l, then reused for q_m -> a_m
    u16* KV = p;                              // kv_m, then reused for kv_l

    // bf16 copies of the activations live in the SECOND HALF of d_out
    // (bytes [128MB,256MB)). That region is only written by the final
    // phase-M GEMM, which launches strictly after the last read of both
    // buffers (phase-M Q and KV GEMMs) — stream-ordered, no race.
    u16* Lb = (u16*)(out + (size_t)32768 * 1024);          // 64 MB
    u16* Mb = Lb + (size_t)32768 * 1024;                   // 64 MB

    // weight fp32 -> bf16 transposes (weights restored each call -> redo each call)
    transpose_f32_bf16<<<dim3(32, 32), 256, 0, stream>>>(Wlq,  WtLq,  1024, 1024);
    transpose_f32_bf16<<<dim3(64, 32), 256, 0, stream>>>(Wlkv, WtLkv, 1024, 2048);
    transpose_f32_bf16<<<dim3(32, 32), 256, 0, stream>>>(Wmq,  WtMq,  1024, 1024);
    transpose_f32_bf16<<<dim3(64, 32), 256, 0, stream>>>(Wmkv, WtMkv, 1024, 2048);
    transpose_f32_bf16<<<dim3(32, 32), 256, 0, stream>>>(Wlo,  WtLo,  1024, 1024);
    transpose_f32_bf16<<<dim3(32, 32), 256, 0, stream>>>(Wmo,  WtMo,  1024, 1024);

    // activation fp32 -> bf16 (once; all 6 GEMMs then take the fast a16 path)
    convert_f32_bf16<<<16384, 256, 0, stream>>>(liquid, Lb);
    convert_f32_bf16<<<16384, 256, 0, stream>>>(mamba,  Mb);

    // ---- phase L: enhanced_liquid ----
    gemm_a16_c16<<<dim3(256, 8),  256, 0, stream>>>(Lb, 1024, WtLq,  blq,  Q,  1024, 1024);
    gemm_a16_c16<<<dim3(256, 16), 256, 0, stream>>>(Mb, 1024, WtMkv, bmkv, KV, 2048, 1024);
    attn8<<<8192, 256, 0, stream>>>(Q, KV, Q, 1024, 2048);
    gemm_a16_c32<<<dim3(256, 8),  256, 0, stream>>>(Q, 1024, WtLo, blo, liquid, 1024,
                                                    out, 1024, 1024);

    // ---- phase M: enhanced_mamba (Q, KV buffers reused) ----
    gemm_a16_c16<<<dim3(256, 8),  256, 0, stream>>>(Mb, 1024, WtMq,  bmq,  Q,  1024, 1024);
    gemm_a16_c16<<<dim3(256, 16), 256, 0, stream>>>(Lb, 1024, WtLkv, blkv, KV, 2048, 1024);
    attn8<<<8192, 256, 0, stream>>>(Q, KV, Q, 1024, 2048);
    // writes over Lb/Mb (dead by now) — last kernel of the call
    gemm_a16_c32<<<dim3(256, 8),  256, 0, stream>>>(Q, 1024, WtMo, bmo, mamba, 1024,
                                                    out + (size_t)32768 * 1024, 1024, 1024);
}